// Round 4
// baseline (43.012 us; speedup 1.0000x reference)
//
#include <hip/hip_runtime.h>
#include <hip/hip_bf16.h>

typedef short  short8 __attribute__((ext_vector_type(8)));
typedef float  f32x4  __attribute__((ext_vector_type(4)));

#define B_N     2048
#define KLTOT   2048
#define NCHUNK  128
#define CHUNK_ROWS 16      // B_N / NCHUNK

// ---- workspace layout (float-sized slots) ----
#define WS_PART  0                         // 128*2048*2 = 524288
#define WS_W2F   (WS_PART + 524288)        // 2048*256 uints
#define WS_W1F   (WS_W2F + 524288)         // 2048*32
#define WS_B1F   (WS_W1F + 65536)          // 2048*32
#define WS_W3P   (WS_B1F + 65536)          // 2048*16
#define WS_B2P   (WS_W3P + 32768)          // 2048*16
#define WS_MU    (WS_B2P + 32768)          // 2048
#define WS_RS    (WS_MU + 2048)            // 2048

__device__ __forceinline__ unsigned int bfb(float f) {
    union { __hip_bfloat16 h; unsigned short u; } cv;
    cv.h = __float2bfloat16(f);
    return (unsigned int)cv.u;
}

__device__ __forceinline__ unsigned int cvtpk(float lo, float hi) {
    unsigned int r;
    asm("v_cvt_pk_bf16_f32 %0, %1, %2" : "=v"(r) : "v"(lo), "v"(hi));
    return r;
}

// ---------------- stats: partial sums over batch chunks ----------------
__global__ __launch_bounds__(256) void stats_partial(const float* __restrict__ x,
                                                     float* __restrict__ part) {
    int c4 = blockIdx.x * 256 + threadIdx.x;          // 0..511 (col groups of 4)
    int chunk = blockIdx.y;                           // 0..127
    const float4* p = (const float4*)(x + (size_t)(chunk * CHUNK_ROWS) * KLTOT) + c4;
    float4 s = {0.f, 0.f, 0.f, 0.f}, s2 = {0.f, 0.f, 0.f, 0.f};
#pragma unroll
    for (int r = 0; r < CHUNK_ROWS; ++r) {
        float4 v = p[(size_t)r * (KLTOT / 4)];
        s.x += v.x; s.y += v.y; s.z += v.z; s.w += v.w;
        s2.x = fmaf(v.x, v.x, s2.x); s2.y = fmaf(v.y, v.y, s2.y);
        s2.z = fmaf(v.z, v.z, s2.z); s2.w = fmaf(v.w, v.w, s2.w);
    }
    float4* o = (float4*)(part + ((size_t)chunk * KLTOT + (size_t)c4 * 4) * 2);
    float4 o0 = {s.x, s2.x, s.y, s2.y};
    float4 o1 = {s.z, s2.z, s.w, s2.w};
    o[0] = o0;
    o[1] = o1;
}

// ---------------- finalize: coalesced reduction over chunks ----------------
// grid 32 blocks x 256 thr; block covers 64 cols, 4 chunk-groups of 32
__global__ __launch_bounds__(256) void stats_finalize(const float* __restrict__ part,
                                                      float* __restrict__ muA,
                                                      float* __restrict__ rsA) {
    __shared__ float red[256][2];
    const int t = threadIdx.x;
    const int c = t & 63, cg = t >> 6;
    const int col = blockIdx.x * 64 + c;
    const float2* p = (const float2*)part;
    float s = 0.f, s2 = 0.f;
#pragma unroll 4
    for (int i = 0; i < 32; ++i) {
        float2 v = p[(size_t)(cg * 32 + i) * KLTOT + col];
        s += v.x; s2 += v.y;
    }
    red[t][0] = s; red[t][1] = s2;
    __syncthreads();
    if (t < 64) {
        float S  = red[t][0] + red[t + 64][0] + red[t + 128][0] + red[t + 192][0];
        float S2 = red[t][1] + red[t + 64][1] + red[t + 128][1] + red[t + 192][1];
        float mu  = S / (float)B_N;
        float var = fmaxf(S2 / (float)B_N - mu * mu, 0.f);
        muA[col] = mu;
        rsA[col] = 1.f / (sqrtf(var) + 1e-8f);
    }
}

// ---------------- prep: pack MFMA-ready weight fragments (standardization folded) ----------------
__global__ __launch_bounds__(256) void prep_w(
    const float* __restrict__ W1, const float* __restrict__ b1,
    const float* __restrict__ W2, const float* __restrict__ b2,
    const float* __restrict__ W3,
    const float* __restrict__ muA, const float* __restrict__ rsA,
    unsigned int* __restrict__ W2f, float* __restrict__ W1f, float* __restrict__ b1f,
    float* __restrict__ W3p, float* __restrict__ b2p)
{
    __shared__ float sW2[4][224];
    const int tid = threadIdx.x;
    const int wv = tid >> 6, l = tid & 63;
    const int col = blockIdx.x * 4 + wv;

    const float* w2c = W2 + (size_t)col * 216;
    if (l < 54) *(float4*)&sW2[wv][l * 4] = ((const float4*)w2c)[l];
    __syncthreads();

    // W2^T fragment (A-operand): A[row=j][k=h], zero-padded, bf16-packed
#pragma unroll
    for (int q = 0; q < 4; ++q) {
        int d = q * 64 + l;
        unsigned int u[2];
#pragma unroll
        for (int half = 0; half < 2; ++half) {
            int idx = d * 2 + half;
            int g = idx >> 7, j = (idx >> 3) & 15, e = idx & 7;
            int h = g * 8 + e;
            float v = (h < 18 && j < 12) ? sW2[wv][h * 12 + j] : 0.f;
            u[half] = bfb(v);
        }
        W2f[(size_t)col * 256 + d] = u[0] | (u[1] << 16);
    }

    const float mu = muA[col], rs = rsA[col];
    // folded: h1 = relu(x*(rs*W1) + (b1 - mu*rs*W1))
    if (l < 32) {
        float w1v = (l < 18) ? W1[(size_t)col * 18 + l] : 0.f;
        float b1v = (l < 18) ? b1[(size_t)col * 18 + l] : 0.f;
        float w1p = w1v * rs;
        W1f[(size_t)col * 32 + l] = w1p;
        b1f[(size_t)col * 32 + l] = fmaf(-mu, w1p, b1v);
    }
    if (l < 16) {
        W3p[(size_t)col * 16 + l] = (l < 12) ? W3[(size_t)col * 12 + l] : 0.f;
        b2p[(size_t)col * 16 + l] = (l < 12) ? b2[(size_t)col * 12 + l] : 0.f;
    }
}

// ---------------- main MFMA kernel ----------------
struct Cols {
    short8 afrag;
    f32x4 w1a, w1b, b1a, b1b;
    f32x4 w3r, b2r;
    float b3v;
};

__device__ __forceinline__ Cols loadc(
    const unsigned int* __restrict__ W2f,
    const float* __restrict__ W1f, const float* __restrict__ b1f,
    const float* __restrict__ W3p, const float* __restrict__ b2p,
    const float* __restrict__ b3, int col, int g, int lj)
{
    Cols c;
    c.afrag = *(const short8*)(W2f + (size_t)col * 256 + (g * 16 + lj) * 4);
    c.w1a = *(const f32x4*)(W1f + (size_t)col * 32 + g * 8);
    c.w1b = *(const f32x4*)(W1f + (size_t)col * 32 + g * 8 + 4);
    c.b1a = *(const f32x4*)(b1f + (size_t)col * 32 + g * 8);
    c.b1b = *(const f32x4*)(b1f + (size_t)col * 32 + g * 8 + 4);
    c.w3r = *(const f32x4*)(W3p + (size_t)col * 16 + g * 4);
    c.b2r = *(const f32x4*)(b2p + (size_t)col * 16 + g * 4);
    c.b3v = b3[col];
    return c;
}

// block = 256 thr (4 waves). tile: 64 cols x 64 batch rows. wave: 16 cols x 4 rowblocks.
__global__ __launch_bounds__(256, 4) void mlp_mfma(
    const float* __restrict__ x,
    const unsigned int* __restrict__ W2f,
    const float* __restrict__ W1f, const float* __restrict__ b1f,
    const float* __restrict__ W3p, const float* __restrict__ b2p,
    const float* __restrict__ b3,
    float* __restrict__ out)
{
    __shared__ float sxs[64 * 68];            // [row][col], pad 68
    const int tid = threadIdx.x;
    const int kl0 = blockIdx.x * 64;
    const int b0  = blockIdx.y * 64;

    // ---- stage RAW x tile [64 rows][64 cols] (standardization folded into W1'/b1') ----
    {
        const int c4 = tid & 15, r0 = tid >> 4;
#pragma unroll
        for (int p = 0; p < 4; ++p) {
            int r = p * 16 + r0;
            f32x4 v = *(const f32x4*)(x + (size_t)(b0 + r) * KLTOT + kl0 + c4 * 4);
            *(f32x4*)&sxs[r * 68 + c4 * 4] = v;
        }
    }
    __syncthreads();

    const int w = tid >> 6, l = tid & 63;
    const int g = l >> 4, lj = l & 15;
    const int colbase = kl0 + w * 16;

    Cols cur = loadc(W2f, W1f, b1f, W3p, b2p, b3, colbase, g, lj);

#pragma unroll 1
    for (int cc = 0; cc < 16; ++cc) {
        // issue next column-set loads NOW; waited at rotation (end of body)
        int nc = (cc + 1) & 15;                 // wraps: redundant L2-hit load on last iter
        Cols nxt = loadc(W2f, W1f, b1f, W3p, b2p, b3, colbase + nc, g, lj);

        const int colloc = w * 16 + cc;
        float xv[4];
#pragma unroll
        for (int rb = 0; rb < 4; ++rb)
            xv[rb] = sxs[(rb * 16 + lj) * 68 + colloc];   // broadcast across g

        float res = 0.f;
#pragma unroll
        for (int rb = 0; rb < 4; ++rb) {
            float xsv = xv[rb];
            float h[8];
#pragma unroll
            for (int e = 0; e < 4; ++e) h[e]     = fmaxf(fmaf(xsv, cur.w1a[e], cur.b1a[e]), 0.f);
#pragma unroll
            for (int e = 0; e < 4; ++e) h[4 + e] = fmaxf(fmaf(xsv, cur.w1b[e], cur.b1b[e]), 0.f);

            union { unsigned int u[4]; short8 s; } bf;
#pragma unroll
            for (int q = 0; q < 4; ++q) bf.u[q] = cvtpk(h[2 * q], h[2 * q + 1]);

            f32x4 acc = { cur.b2r[0], cur.b2r[1], cur.b2r[2], cur.b2r[3] };
            acc = __builtin_amdgcn_mfma_f32_16x16x32_bf16(cur.afrag, bf.s, acc, 0, 0, 0);

            float pp = 0.f;
#pragma unroll
            for (int r = 0; r < 4; ++r)
                pp = fmaf(fmaxf(acc[r], 0.f), cur.w3r[r], pp);
            pp += __shfl_xor(pp, 16, 64);
            pp += __shfl_xor(pp, 32, 64);

            if (rb == g) res = pp + cur.b3v;    // each lane keeps the rowblock matching its g
        }
        sxs[(g * 16 + lj) * 68 + colloc] = res; // unpredicated: 64 lanes cover 64 rows
        cur = nxt;
    }
    __syncthreads();

    // ---- coalesced float4 store of the 64x64 tile ----
#pragma unroll
    for (int p = 0; p < 4; ++p) {
        int idx = p * 256 + tid;
        int b = idx >> 4, c4 = idx & 15;
        f32x4 v = *(const f32x4*)&sxs[b * 68 + c4 * 4];
        *(f32x4*)(out + (size_t)(b0 + b) * KLTOT + kl0 + c4 * 4) = v;
    }
}

extern "C" void kernel_launch(void* const* d_in, const int* in_sizes, int n_in,
                              void* d_out, int out_size, void* d_ws, size_t ws_size,
                              hipStream_t stream) {
    const float* x  = (const float*)d_in[0];
    const float* W1 = (const float*)d_in[1];
    const float* b1 = (const float*)d_in[2];
    const float* W2 = (const float*)d_in[3];
    const float* b2 = (const float*)d_in[4];
    const float* W3 = (const float*)d_in[5];
    const float* b3 = (const float*)d_in[6];
    float* out = (float*)d_out;

    float* ws = (float*)d_ws;
    float*        part = ws + WS_PART;
    unsigned int* W2f  = (unsigned int*)(ws + WS_W2F);
    float*        W1f  = ws + WS_W1F;
    float*        b1f  = ws + WS_B1F;
    float*        W3p  = ws + WS_W3P;
    float*        b2p  = ws + WS_B2P;
    float*        muA  = ws + WS_MU;
    float*        rsA  = ws + WS_RS;

    stats_partial <<<dim3(KLTOT / 1024, NCHUNK), 256, 0, stream>>>(x, part);
    stats_finalize<<<dim3(KLTOT / 64),            256, 0, stream>>>(part, muA, rsA);
    prep_w        <<<dim3(KLTOT / 4),             256, 0, stream>>>(W1, b1, W2, b2, W3,
                                                                    muA, rsA,
                                                                    W2f, W1f, b1f, W3p, b2p);
    mlp_mfma      <<<dim3(KLTOT / 64, B_N / 64),  256, 0, stream>>>(
        x, W2f, W1f, b1f, W3p, b2p, b3, out);
}

// Round 5
// 37.145 us; speedup vs baseline: 1.1579x; 1.1579x over previous
//
#include <hip/hip_runtime.h>
#include <hip/hip_bf16.h>

typedef short  short8 __attribute__((ext_vector_type(8)));
typedef float  f32x4  __attribute__((ext_vector_type(4)));

#define B_N     2048
#define KLTOT   2048
#define NCHUNK  128
#define CHUNK_ROWS 16      // B_N / NCHUNK

// ---- workspace layout (float-sized slots) ----
#define WS_PART  0                         // 128*2048*2 = 524288
#define WS_W2F   (WS_PART + 524288)        // 2048*256 uints
#define WS_W1F   (WS_W2F + 524288)         // 2048*32
#define WS_B1F   (WS_W1F + 65536)          // 2048*32
#define WS_W3P   (WS_B1F + 65536)          // 2048*16
#define WS_B2P   (WS_W3P + 32768)          // 2048*16
#define WS_MU    (WS_B2P + 32768)          // 2048
#define WS_RS    (WS_MU + 2048)            // 2048

// 5/5/4/4 h-slot packing: k-slot s = g*8+e maps to hidden unit hmap(g,e)
__device__ __host__ __forceinline__ int hmap(int g, int e) {
    return (g < 2) ? ((e < 5) ? g * 5 + e : -1)
                   : ((e < 4) ? 10 + (g - 2) * 4 + e : -1);
}

__device__ __forceinline__ unsigned int bfb(float f) {
    union { __hip_bfloat16 h; unsigned short u; } cv;
    cv.h = __float2bfloat16(f);
    return (unsigned int)cv.u;
}

__device__ __forceinline__ unsigned int cvtpk(float lo, float hi) {
    unsigned int r;
    asm("v_cvt_pk_bf16_f32 %0, %1, %2" : "=v"(r) : "v"(lo), "v"(hi));
    return r;
}

// ---------------- stats: partial sums over batch chunks ----------------
__global__ __launch_bounds__(256) void stats_partial(const float* __restrict__ x,
                                                     float* __restrict__ part) {
    int c4 = blockIdx.x * 256 + threadIdx.x;          // 0..511
    int chunk = blockIdx.y;                           // 0..127
    const float4* p = (const float4*)(x + (size_t)(chunk * CHUNK_ROWS) * KLTOT) + c4;
    float4 s = {0.f, 0.f, 0.f, 0.f}, s2 = {0.f, 0.f, 0.f, 0.f};
#pragma unroll
    for (int r = 0; r < CHUNK_ROWS; ++r) {
        float4 v = p[(size_t)r * (KLTOT / 4)];
        s.x += v.x; s.y += v.y; s.z += v.z; s.w += v.w;
        s2.x = fmaf(v.x, v.x, s2.x); s2.y = fmaf(v.y, v.y, s2.y);
        s2.z = fmaf(v.z, v.z, s2.z); s2.w = fmaf(v.w, v.w, s2.w);
    }
    float4* o = (float4*)(part + ((size_t)chunk * KLTOT + (size_t)c4 * 4) * 2);
    float4 o0 = {s.x, s2.x, s.y, s2.y};
    float4 o1 = {s.z, s2.z, s.w, s2.w};
    o[0] = o0;
    o[1] = o1;
}

// ---------------- finalize: coalesced reduction over chunks ----------------
__global__ __launch_bounds__(256) void stats_finalize(const float* __restrict__ part,
                                                      float* __restrict__ muA,
                                                      float* __restrict__ rsA) {
    __shared__ float red[256][2];
    const int t = threadIdx.x;
    const int c = t & 63, cg = t >> 6;
    const int col = blockIdx.x * 64 + c;
    const float2* p = (const float2*)part;
    float s = 0.f, s2 = 0.f;
#pragma unroll 4
    for (int i = 0; i < 32; ++i) {
        float2 v = p[(size_t)(cg * 32 + i) * KLTOT + col];
        s += v.x; s2 += v.y;
    }
    red[t][0] = s; red[t][1] = s2;
    __syncthreads();
    if (t < 64) {
        float S  = red[t][0] + red[t + 64][0] + red[t + 128][0] + red[t + 192][0];
        float S2 = red[t][1] + red[t + 64][1] + red[t + 128][1] + red[t + 192][1];
        float mu  = S / (float)B_N;
        float var = fmaxf(S2 / (float)B_N - mu * mu, 0.f);
        muA[col] = mu;
        rsA[col] = 1.f / (sqrtf(var) + 1e-8f);
    }
}

// ---------------- prep: pack weights (stats folded, 5/5/4/4 slot layout) ----------------
__global__ __launch_bounds__(256) void prep_w(
    const float* __restrict__ W1, const float* __restrict__ b1,
    const float* __restrict__ W2, const float* __restrict__ b2,
    const float* __restrict__ W3,
    const float* __restrict__ muA, const float* __restrict__ rsA,
    unsigned int* __restrict__ W2f, float* __restrict__ W1f, float* __restrict__ b1f,
    float* __restrict__ W3p, float* __restrict__ b2p)
{
    __shared__ float sW2[4][224];
    const int tid = threadIdx.x;
    const int wv = tid >> 6, l = tid & 63;
    const int col = blockIdx.x * 4 + wv;

    const float* w2c = W2 + (size_t)col * 216;
    if (l < 54) *(float4*)&sW2[wv][l * 4] = ((const float4*)w2c)[l];
    __syncthreads();

    // A-fragment: A[row=j][slot s] = W2[hmap(s)][j], zero-padded, bf16-packed
#pragma unroll
    for (int q = 0; q < 4; ++q) {
        int d = q * 64 + l;
        unsigned int u[2];
#pragma unroll
        for (int half = 0; half < 2; ++half) {
            int idx = d * 2 + half;
            int gg = idx >> 7, j = (idx >> 3) & 15, e = idx & 7;
            int h = hmap(gg, e);
            float v = (h >= 0 && j < 12) ? sW2[wv][h * 12 + j] : 0.f;
            u[half] = bfb(v);
        }
        W2f[(size_t)col * 256 + d] = u[0] | (u[1] << 16);
    }

    const float mu = muA[col], rs = rsA[col];
    // folded standardization: h1 = relu(x*(rs*W1) + (b1 - mu*rs*W1)), in slot layout
    if (l < 32) {
        int gg = l >> 3, e = l & 7;
        int h = hmap(gg, e);
        float w1o = 0.f, b1o = 0.f;
        if (h >= 0) {
            float w1raw = W1[(size_t)col * 18 + h];
            w1o = w1raw * rs;
            b1o = fmaf(-mu, w1o, b1[(size_t)col * 18 + h]);
        }
        W1f[(size_t)col * 32 + l] = w1o;
        b1f[(size_t)col * 32 + l] = b1o;
    }
    if (l < 16) {
        W3p[(size_t)col * 16 + l] = (l < 12) ? W3[(size_t)col * 12 + l] : 0.f;
        b2p[(size_t)col * 16 + l] = (l < 12) ? b2[(size_t)col * 12 + l] : 0.f;
    }
}

// ---------------- main MFMA kernel: wave-per-column ----------------
// block = 512 thr (8 waves) = 16 cols x 128 batch rows; wave w owns column w... (w<16? no:
// 8 waves, 16 cols -> wave owns 2 cols? NO: block covers 16 cols via 8 waves? )
// Correction: block = 16 cols x 128 rows staged, 8 waves; waves 0..7 own cols 0..7? That
// leaves 8 cols unowned. Instead: wave w owns cols {w, w+8}? Simpler: block = 8 cols.
// FINAL LAYOUT: block = 512 thr = 8 waves; tile = 16 cols x 128 rows; wave w computes
// column w for rb 0..7 THEN column w+8 for rb 0..7 (two passes, constants reloaded once).
#define LJS 12          // lj stride (dwords) in LDS tile
#define CS  196         // col stride  (16*12 + 4 pad)

__global__ __launch_bounds__(512, 4) void mlp_mfma(
    const float* __restrict__ x,
    const unsigned int* __restrict__ W2f,
    const float* __restrict__ W1f, const float* __restrict__ b1f,
    const float* __restrict__ W3p, const float* __restrict__ b2p,
    const float* __restrict__ b3,
    float* __restrict__ out)
{
    __shared__ float tile[16 * CS];
    const int tid = threadIdx.x;
    const int kl0 = blockIdx.x * 16;
    const int b0  = blockIdx.y * 128;

    // ---- stage x [128 rows][16 cols] -> tile[c][r&15][r>>4] ----
    {
        const int r = tid >> 2, c4 = tid & 3;
        f32x4 v = *(const f32x4*)(x + (size_t)(b0 + r) * KLTOT + kl0 + c4 * 4);
        const int base = (r & 15) * LJS + (r >> 4);
#pragma unroll
        for (int e = 0; e < 4; ++e)
            tile[(c4 * 4 + e) * CS + base] = v[e];
    }
    __syncthreads();

    const int w = tid >> 6, l = tid & 63;
    const int g = l >> 4, lj = l & 15;

#pragma unroll 1
    for (int half = 0; half < 2; ++half) {
        const int cloc = w + half * 8;
        const int col = kl0 + cloc;

        // per-column constants (once per 8 MFMAs)
        short8 afrag = *(const short8*)(W2f + (size_t)col * 256 + (g * 16 + lj) * 4);
        f32x4 w1v = *(const f32x4*)(W1f + (size_t)col * 32 + g * 8);
        float w1s = W1f[(size_t)col * 32 + g * 8 + 4];
        f32x4 b1v = *(const f32x4*)(b1f + (size_t)col * 32 + g * 8);
        float b1s = b1f[(size_t)col * 32 + g * 8 + 4];
        f32x4 w3r = *(const f32x4*)(W3p + (size_t)col * 16 + g * 4);
        f32x4 b2r = *(const f32x4*)(b2p + (size_t)col * 16 + g * 4);
        float b3v = b3[col];

        // all 8 x values for this lane up front (rows lj, lj+16, ..., lj+112)
        f32x4 xq0, xq1;
        {
            const float* xb = &tile[cloc * CS + lj * LJS];
            xq0 = *(const f32x4*)(xb);
            xq1 = *(const f32x4*)(xb + 4);
        }

        float res0 = 0.f, res1 = 0.f;
#pragma unroll
        for (int rb = 0; rb < 8; ++rb) {
            float xsv = (rb < 4) ? xq0[rb & 3] : xq1[rb & 3];
            float h0 = fmaxf(fmaf(xsv, w1v[0], b1v[0]), 0.f);
            float h1 = fmaxf(fmaf(xsv, w1v[1], b1v[1]), 0.f);
            float h2 = fmaxf(fmaf(xsv, w1v[2], b1v[2]), 0.f);
            float h3 = fmaxf(fmaf(xsv, w1v[3], b1v[3]), 0.f);
            float h4 = fmaxf(fmaf(xsv, w1s,    b1s),    0.f);
            union { unsigned int u[4]; short8 s; } bf;
            bf.u[0] = cvtpk(h0, h1);
            bf.u[1] = cvtpk(h2, h3);
            bf.u[2] = cvtpk(h4, h4);     // slot5 don't-care: A slot5 = 0
            bf.u[3] = 0;                 // slots 6,7: A = 0

            f32x4 acc = { b2r[0], b2r[1], b2r[2], b2r[3] };
            acc = __builtin_amdgcn_mfma_f32_16x16x32_bf16(afrag, bf.s, acc, 0, 0, 0);

            float pp = 0.f;
#pragma unroll
            for (int r = 0; r < 4; ++r)
                pp = fmaf(fmaxf(acc[r], 0.f), w3r[r], pp);
            pp += __shfl_xor(pp, 16, 64);
            pp += __shfl_xor(pp, 32, 64);
            float rv = pp + b3v;
            if ((rb & 3) == g) {
                if (rb < 4) res0 = rv; else res1 = rv;
            }
        }

        // write results over the (dead) x slots of this column: rc = g and g+4
        {
            float* tb = &tile[cloc * CS + lj * LJS + g];
            tb[0] = res0;
            tb[4] = res1;
        }
    }
    __syncthreads();

    // ---- coalesced store: out[r][c] from tile[c][r&15][r>>4] ----
    {
        const int r = tid >> 2, c4 = tid & 3;
        const int base = (r & 15) * LJS + (r >> 4);
        f32x4 v;
#pragma unroll
        for (int e = 0; e < 4; ++e)
            v[e] = tile[(c4 * 4 + e) * CS + base];
        *(f32x4*)(out + (size_t)(b0 + r) * KLTOT + kl0 + c4 * 4) = v;
    }
}

extern "C" void kernel_launch(void* const* d_in, const int* in_sizes, int n_in,
                              void* d_out, int out_size, void* d_ws, size_t ws_size,
                              hipStream_t stream) {
    const float* x  = (const float*)d_in[0];
    const float* W1 = (const float*)d_in[1];
    const float* b1 = (const float*)d_in[2];
    const float* W2 = (const float*)d_in[3];
    const float* b2 = (const float*)d_in[4];
    const float* W3 = (const float*)d_in[5];
    const float* b3 = (const float*)d_in[6];
    float* out = (float*)d_out;

    float* ws = (float*)d_ws;
    float*        part = ws + WS_PART;
    unsigned int* W2f  = (unsigned int*)(ws + WS_W2F);
    float*        W1f  = ws + WS_W1F;
    float*        b1f  = ws + WS_B1F;
    float*        W3p  = ws + WS_W3P;
    float*        b2p  = ws + WS_B2P;
    float*        muA  = ws + WS_MU;
    float*        rsA  = ws + WS_RS;

    stats_partial <<<dim3(2, NCHUNK),      256, 0, stream>>>(x, part);
    stats_finalize<<<dim3(KLTOT / 64),     256, 0, stream>>>(part, muA, rsA);
    prep_w        <<<dim3(KLTOT / 4),      256, 0, stream>>>(W1, b1, W2, b2, W3,
                                                             muA, rsA,
                                                             W2f, W1f, b1f, W3p, b2p);
    mlp_mfma      <<<dim3(KLTOT / 16, B_N / 128), 512, 0, stream>>>(
        x, W2f, W1f, b1f, W3p, b2p, b3, out);
}

// Round 7
// 36.318 us; speedup vs baseline: 1.1843x; 1.0228x over previous
//
#include <hip/hip_runtime.h>
#include <hip/hip_fp16.h>

typedef _Float16 half8  __attribute__((ext_vector_type(8)));
typedef _Float16 half4  __attribute__((ext_vector_type(4)));
typedef _Float16 h2v    __attribute__((ext_vector_type(2)));
typedef __fp16   fp16x2 __attribute__((ext_vector_type(2)));
typedef float    f32x4  __attribute__((ext_vector_type(4)));

#define B_N     2048
#define KLTOT   2048
#define NCHUNK  128
#define CHUNK_ROWS 16      // B_N / NCHUNK

// ---- workspace layout (dword slots) ----
#define WS_PART  0                         // 128*2048*2 = 524288
#define WS_W2F   (WS_PART + 524288)        // 2048*256 uints (f16-packed A-frags)
#define WS_W1H   (WS_W2F + 524288)         // 2048*16 uints (f16 pairs)
#define WS_B1H   (WS_W1H + 32768)          // 2048*16 uints
#define WS_W3H   (WS_B1H + 32768)          // 2048*8 uints (f16 pairs, j padded to 16)
#define WS_B2P   (WS_W3H + 16384)          // 2048*16 f32
#define WS_MU    (WS_B2P + 32768)          // 2048
#define WS_RS    (WS_MU + 2048)            // 2048

// 5/5/4/4 h-slot packing: k-slot s = g*8+e maps to hidden unit hmap(g,e)
__device__ __forceinline__ int hmap(int g, int e) {
    return (g < 2) ? ((e < 5) ? g * 5 + e : -1)
                   : ((e < 4) ? 10 + (g - 2) * 4 + e : -1);
}

__device__ __forceinline__ unsigned int f16b(float f) {
    union { _Float16 h; unsigned short u; } c;
    c.h = (_Float16)f;
    return (unsigned int)c.u;
}

// ---------------- stats: partial sums over batch chunks ----------------
__global__ __launch_bounds__(256) void stats_partial(const float* __restrict__ x,
                                                     float* __restrict__ part) {
    int c4 = blockIdx.x * 256 + threadIdx.x;          // 0..511
    int chunk = blockIdx.y;                           // 0..127
    const float4* p = (const float4*)(x + (size_t)(chunk * CHUNK_ROWS) * KLTOT) + c4;
    float4 s = {0.f, 0.f, 0.f, 0.f}, s2 = {0.f, 0.f, 0.f, 0.f};
#pragma unroll
    for (int r = 0; r < CHUNK_ROWS; ++r) {
        float4 v = p[(size_t)r * (KLTOT / 4)];
        s.x += v.x; s.y += v.y; s.z += v.z; s.w += v.w;
        s2.x = fmaf(v.x, v.x, s2.x); s2.y = fmaf(v.y, v.y, s2.y);
        s2.z = fmaf(v.z, v.z, s2.z); s2.w = fmaf(v.w, v.w, s2.w);
    }
    float4* o = (float4*)(part + ((size_t)chunk * KLTOT + (size_t)c4 * 4) * 2);
    float4 o0 = {s.x, s2.x, s.y, s2.y};
    float4 o1 = {s.z, s2.z, s.w, s2.w};
    o[0] = o0;
    o[1] = o1;
}

// ---------------- finalize: coalesced reduction over chunks ----------------
__global__ __launch_bounds__(256) void stats_finalize(const float* __restrict__ part,
                                                      float* __restrict__ muA,
                                                      float* __restrict__ rsA) {
    __shared__ float red[256][2];
    const int t = threadIdx.x;
    const int c = t & 63, cg = t >> 6;
    const int col = blockIdx.x * 64 + c;
    const float2* p = (const float2*)part;
    float s = 0.f, s2 = 0.f;
#pragma unroll 4
    for (int i = 0; i < 32; ++i) {
        float2 v = p[(size_t)(cg * 32 + i) * KLTOT + col];
        s += v.x; s2 += v.y;
    }
    red[t][0] = s; red[t][1] = s2;
    __syncthreads();
    if (t < 64) {
        float S  = red[t][0] + red[t + 64][0] + red[t + 128][0] + red[t + 192][0];
        float S2 = red[t][1] + red[t + 64][1] + red[t + 128][1] + red[t + 192][1];
        float mu  = S / (float)B_N;
        float var = fmaxf(S2 / (float)B_N - mu * mu, 0.f);
        muA[col] = mu;
        rsA[col] = 1.f / (sqrtf(var) + 1e-8f);
    }
}

// ---------------- prep: pack f16 weights (stats folded, 5/5/4/4 slots) ----------------
__global__ __launch_bounds__(256) void prep_w(
    const float* __restrict__ W1, const float* __restrict__ b1,
    const float* __restrict__ W2, const float* __restrict__ b2,
    const float* __restrict__ W3,
    const float* __restrict__ muA, const float* __restrict__ rsA,
    unsigned int* __restrict__ W2f,
    unsigned int* __restrict__ W1h, unsigned int* __restrict__ b1h,
    unsigned int* __restrict__ W3h, float* __restrict__ b2p)
{
    __shared__ float sW2[4][224];
    const int tid = threadIdx.x;
    const int wv = tid >> 6, l = tid & 63;
    const int col = blockIdx.x * 4 + wv;

    const float* w2c = W2 + (size_t)col * 216;
    if (l < 54) *(float4*)&sW2[wv][l * 4] = ((const float4*)w2c)[l];
    __syncthreads();

    // A1-fragment: A[row=j][slot s] = W2[hmap(s)][j], zero-padded, f16-packed
#pragma unroll
    for (int q = 0; q < 4; ++q) {
        int d = q * 64 + l;
        unsigned int u[2];
#pragma unroll
        for (int half = 0; half < 2; ++half) {
            int idx = d * 2 + half;
            int gg = idx >> 7, j = (idx >> 3) & 15, e = idx & 7;
            int h = hmap(gg, e);
            float v = (h >= 0 && j < 12) ? sW2[wv][h * 12 + j] : 0.f;
            u[half] = f16b(v);
        }
        W2f[(size_t)col * 256 + d] = u[0] | (u[1] << 16);
    }

    const float mu = muA[col], rs = rsA[col];
    // W1h/b1h: f16 pairs per (g, q): slots (2q, 2q+1); folded standardization
    if (l < 16) {
        int gg = l >> 2, q = l & 3;
        unsigned int wu = 0, bu = 0;
        if (q < 3) {
            float w0 = 0.f, b0 = 0.f, w1v = 0.f, b1v = 0.f;
            int h0 = hmap(gg, q * 2), h1_ = hmap(gg, q * 2 + 1);
            if (h0 >= 0) {
                w0 = W1[(size_t)col * 18 + h0] * rs;
                b0 = fmaf(-mu, w0, b1[(size_t)col * 18 + h0]);
            }
            if (h1_ >= 0) {
                w1v = W1[(size_t)col * 18 + h1_] * rs;
                b1v = fmaf(-mu, w1v, b1[(size_t)col * 18 + h1_]);
            }
            wu = f16b(w0) | (f16b(w1v) << 16);
            bu = f16b(b0) | (f16b(b1v) << 16);
        }
        W1h[(size_t)col * 16 + l] = wu;
        b1h[(size_t)col * 16 + l] = bu;
    }
    // W3h: f16 pairs, j padded 12->16 with 0
    if (l < 8) {
        int j0 = 2 * l, j1 = 2 * l + 1;
        float v0 = (j0 < 12) ? W3[(size_t)col * 12 + j0] : 0.f;
        float v1 = (j1 < 12) ? W3[(size_t)col * 12 + j1] : 0.f;
        W3h[(size_t)col * 8 + l] = f16b(v0) | (f16b(v1) << 16);
    }
    if (l < 16)
        b2p[(size_t)col * 16 + l] = (l < 12) ? b2[(size_t)col * 12 + l] : 0.f;
}

// ---------------- main kernel: wave-per-column, dual chained MFMA ----------------
#define LJS 12          // lj stride (dwords) in LDS tile
#define CS  196         // col stride (16*12 + 4 pad)

__global__ __launch_bounds__(512, 4) void mlp_mfma(
    const float* __restrict__ x,
    const unsigned int* __restrict__ W2f,
    const unsigned int* __restrict__ W1h, const unsigned int* __restrict__ b1h,
    const unsigned int* __restrict__ W3h, const float* __restrict__ b2p,
    const float* __restrict__ b3,
    float* __restrict__ out)
{
    __shared__ float tile[16 * CS];
    const int tid = threadIdx.x;
    const int kl0 = blockIdx.x * 16;
    const int b0  = blockIdx.y * 128;

    // ---- stage x [128 rows][16 cols] -> tile[c][r&15][r>>4] ----
    {
        const int r = tid >> 2, c4 = tid & 3;
        f32x4 v = *(const f32x4*)(x + (size_t)(b0 + r) * KLTOT + kl0 + c4 * 4);
        const int base = (r & 15) * LJS + (r >> 4);
#pragma unroll
        for (int e = 0; e < 4; ++e)
            tile[(c4 * 4 + e) * CS + base] = v[e];
    }
    __syncthreads();

    const int w = tid >> 6, l = tid & 63;
    const int g = l >> 4, lj = l & 15;
    const h2v z2 = {(_Float16)0.f, (_Float16)0.f};
    const f32x4 zc = {0.f, 0.f, 0.f, 0.f};

#pragma unroll 1
    for (int half = 0; half < 2; ++half) {
        const int cloc = w + half * 8;
        const int col = kl0 + cloc;

        // per-column constants (once per 8 dual-MFMAs)
        union { uint4 u; half8 h; } af;
        af.u = ((const uint4*)W2f)[(size_t)col * 64 + g * 16 + lj];
        union { uint4 u; h2v p[4]; } w1u, b1u;
        w1u.u = ((const uint4*)W1h)[(size_t)col * 4 + g];
        b1u.u = ((const uint4*)b1h)[(size_t)col * 4 + g];
        union { uint2 u; half4 h; } a2;
        a2.u = ((const uint2*)W3h)[(size_t)col * 4 + g];
        f32x4 b2r = ((const f32x4*)b2p)[(size_t)col * 4 + g];
        float b3v = b3[col];

        // all 8 x values for this lane up front (rows lj, lj+16, ..., lj+112)
        f32x4 xq0, xq1;
        {
            const float* xb = &tile[cloc * CS + lj * LJS];
            xq0 = *(const f32x4*)(xb);
            xq1 = *(const f32x4*)(xb + 4);
        }

        float resx = 0.f, resy = 0.f;
#pragma unroll
        for (int rb = 0; rb < 8; ++rb) {
            float xsv = (rb < 4) ? xq0[rb & 3] : xq1[rb & 3];
            _Float16 xh = (_Float16)xsv;
            h2v x2 = {xh, xh};

            union { h2v p[4]; half8 h; } bf;
            bf.p[0] = __builtin_elementwise_max(x2 * w1u.p[0] + b1u.p[0], z2);
            bf.p[1] = __builtin_elementwise_max(x2 * w1u.p[1] + b1u.p[1], z2);
            bf.p[2] = __builtin_elementwise_max(x2 * w1u.p[2] + b1u.p[2], z2);
            bf.p[3] = z2;

            // MFMA1: Z[j(16) x b(16)] = W2^T(j x 32h) * H1(32h x b) + b2
            f32x4 acc = __builtin_amdgcn_mfma_f32_16x16x32_f16(af.h, bf.h, b2r, 0, 0, 0);

            // relu + f16-pack: D1 layout == B-operand layout of 16x16x16 MFMA
            union { fp16x2 c[2]; half4 h; } zf;
            zf.c[0] = __builtin_amdgcn_cvt_pkrtz(fmaxf(acc[0], 0.f), fmaxf(acc[1], 0.f));
            zf.c[1] = __builtin_amdgcn_cvt_pkrtz(fmaxf(acc[2], 0.f), fmaxf(acc[3], 0.f));

            // MFMA2: out[b] = W3^T(k=j) * relu(Z)(j x b) — reduction on matrix pipe
            f32x4 acc2 = __builtin_amdgcn_mfma_f32_16x16x16f16(a2.h, zf.h, zc, 0, 0, 0);

            float rv = acc2[0] + b3v;
            if ((rb >> 1) == g) {        // lane group g keeps rb = 2g, 2g+1
                if (rb & 1) resy = rv; else resx = rv;
            }
        }

        // write results over the (dead) x slots of this column: rc = 2g, 2g+1
        {
            float2 rr = { resx, resy };
            *(float2*)&tile[cloc * CS + lj * LJS + g * 2] = rr;
        }
    }
    __syncthreads();

    // ---- coalesced store: out[r][c] from tile[c][r&15][r>>4] ----
    {
        const int r = tid >> 2, c4 = tid & 3;
        const int base = (r & 15) * LJS + (r >> 4);
        f32x4 v;
#pragma unroll
        for (int e = 0; e < 4; ++e)
            v[e] = tile[(c4 * 4 + e) * CS + base];
        *(f32x4*)(out + (size_t)(b0 + r) * KLTOT + kl0 + c4 * 4) = v;
    }
}

extern "C" void kernel_launch(void* const* d_in, const int* in_sizes, int n_in,
                              void* d_out, int out_size, void* d_ws, size_t ws_size,
                              hipStream_t stream) {
    const float* x  = (const float*)d_in[0];
    const float* W1 = (const float*)d_in[1];
    const float* b1 = (const float*)d_in[2];
    const float* W2 = (const float*)d_in[3];
    const float* b2 = (const float*)d_in[4];
    const float* W3 = (const float*)d_in[5];
    const float* b3 = (const float*)d_in[6];
    float* out = (float*)d_out;

    float* ws = (float*)d_ws;
    float*        part = ws + WS_PART;
    unsigned int* W2f  = (unsigned int*)(ws + WS_W2F);
    unsigned int* W1h  = (unsigned int*)(ws + WS_W1H);
    unsigned int* b1h  = (unsigned int*)(ws + WS_B1H);
    unsigned int* W3h  = (unsigned int*)(ws + WS_W3H);
    float*        b2p  = ws + WS_B2P;
    float*        muA  = ws + WS_MU;
    float*        rsA  = ws + WS_RS;

    stats_partial <<<dim3(2, NCHUNK),      256, 0, stream>>>(x, part);
    stats_finalize<<<dim3(KLTOT / 64),     256, 0, stream>>>(part, muA, rsA);
    prep_w        <<<dim3(KLTOT / 4),      256, 0, stream>>>(W1, b1, W2, b2, W3,
                                                             muA, rsA,
                                                             W2f, W1h, b1h, W3h, b2p);
    mlp_mfma      <<<dim3(KLTOT / 16, B_N / 128), 512, 0, stream>>>(
        x, W2f, W1h, b1h, W3h, b2p, b3, out);
}